// Round 6
// baseline (584.761 us; speedup 1.0000x reference)
//
#include <hip/hip_runtime.h>
#include <math.h>

#define BB 4
#define NN 8192
#define MM 2048
#define CC 64
#define KNB 32
#define CIN 67   // 3 + CC
#define H1 64
#define H2 128

// ---------------- init: zero per-batch maxnorm cells ----------------
__global__ void init_kernel(int* maxnorm) {
    if (threadIdx.x < BB) maxnorm[threadIdx.x] = 0;
}

// ---------------- c2 precompute: sum of squares per point, exact same formula ----------------
__global__ __launch_bounds__(256) void c2_kernel(const float* __restrict__ coord,
                                                 float* __restrict__ c2buf) {
    const int t = blockIdx.x * 256 + threadIdx.x;   // t in [0, BB*NN)
    if (t < BB * NN) {
        float cx = coord[t * 3 + 0], cy = coord[t * 3 + 1], cz = coord[t * 3 + 2];
        c2buf[t] = __fadd_rn(__fadd_rn(__fmul_rn(cx, cx), __fmul_rn(cy, cy)), __fmul_rn(cz, cz));
    }
}

// ---------------- kNN: one block per anchor (round-1 selection; wave-parallel rescan) ----------------
__global__ __launch_bounds__(256, 4) void knn_kernel(
    const float* __restrict__ coord, const float* __restrict__ anchor_coord,
    const float* __restrict__ c2buf,
    int* __restrict__ idxbuf, int* __restrict__ maxnorm)
{
    __shared__ float d2s[256 * 33];   // padded [chunk][33]
    __shared__ float cmin[256];
    __shared__ int   carg[256];
    __shared__ float rd[4];
    __shared__ int   ri[4];
    __shared__ int   sel_s[KNB];

    const int anchor = blockIdx.x;
    const int b  = anchor >> 11;          // / MM
    const int mi = anchor & (MM - 1);
    const int tid = threadIdx.x;
    const int lane = tid & 63;

    const float ax = anchor_coord[(b * MM + mi) * 3 + 0];
    const float ay = anchor_coord[(b * MM + mi) * 3 + 1];
    const float az = anchor_coord[(b * MM + mi) * 3 + 2];
    const float a2 = __fadd_rn(__fadd_rn(__fmul_rn(ax, ax), __fmul_rn(ay, ay)), __fmul_rn(az, az));

    const float* cb  = coord + (size_t)b * NN * 3;
    const float* c2b = c2buf + (size_t)b * NN;

    // distances (reference formula; c2 preloaded, bitwise identical to inline compute)
    for (int i = tid; i < NN; i += 256) {
        float cx = cb[i * 3 + 0], cy = cb[i * 3 + 1], cz = cb[i * 3 + 2];
        float c2 = c2b[i];
        float dt = __fadd_rn(__fadd_rn(__fmul_rn(ax, cx), __fmul_rn(ay, cy)), __fmul_rn(az, cz));
        float d2 = __fadd_rn(__fsub_rn(a2, __fmul_rn(2.0f, dt)), c2);
        d2s[(i >> 5) * 33 + (i & 31)] = d2;
    }
    __syncthreads();

    // per-chunk min (chunk = 32 points, one per thread)
    {
        float bd = INFINITY; int bi = NN;
        const int base = tid * 33;
        #pragma unroll
        for (int j = 0; j < 32; j++) {
            float v = d2s[base + j];
            if (v < bd) { bd = v; bi = tid * 32 + j; }
        }
        cmin[tid] = bd; carg[tid] = bi;
    }
    __syncthreads();

    // 32 rounds of hierarchical argmin (tie-break: lower global index)
    for (int it = 0; it < KNB; it++) {
        float v = cmin[tid]; int gi = carg[tid];
        #pragma unroll
        for (int off = 32; off; off >>= 1) {
            float ov = __shfl_xor(v, off);
            int   og = __shfl_xor(gi, off);
            if (ov < v || (ov == v && og < gi)) { v = ov; gi = og; }
        }
        if ((tid & 63) == 0) { rd[tid >> 6] = v; ri[tid >> 6] = gi; }
        __syncthreads();
        float fv = rd[0]; int fgi = ri[0];
        #pragma unroll
        for (int ww = 1; ww < 4; ww++) {
            float wv = rd[ww]; int wg = ri[ww];
            if (wv < fv || (wv == fv && wg < fgi)) { fv = wv; fgi = wg; }
        }
        const int wc = fgi >> 5;
        // owner WAVE removes winner and rescans the chunk in parallel
        // (lex-min butterfly == serial strict-< scan: lowest index on ties)
        if ((tid >> 6) == (wc >> 6)) {
            const int j32 = lane & 31;
            const int gidx = wc * 32 + j32;
            float x = d2s[wc * 33 + j32];
            if (gidx == fgi) x = INFINITY;                         // in-register removal
            if (lane == (fgi & 31)) d2s[wc * 33 + j32] = INFINITY; // persistent removal
            int xi = gidx;
            #pragma unroll
            for (int off = 32; off; off >>= 1) {
                float ox = __shfl_xor(x, off);
                int   oi = __shfl_xor(xi, off);
                if (ox < x || (ox == x && oi < xi)) { x = ox; xi = oi; }
            }
            if (lane == 0) { cmin[wc] = x; carg[wc] = xi; }
        }
        if (tid == 0) sel_s[it] = fgi;
        __syncthreads();
    }

    // write indices; per-batch max ||delta||
    float nrm = 0.0f;
    if (tid < KNB) {
        int j = sel_s[tid];
        idxbuf[anchor * KNB + tid] = j;
        float dx = __fsub_rn(cb[j * 3 + 0], ax);
        float dy = __fsub_rn(cb[j * 3 + 1], ay);
        float dz = __fsub_rn(cb[j * 3 + 2], az);
        nrm = sqrtf(dx * dx + dy * dy + dz * dz);
    }
    if (tid < 64) {
        #pragma unroll
        for (int off = 32; off; off >>= 1) nrm = fmaxf(nrm, __shfl_xor(nrm, off));
        if (tid == 0) atomicMax(&maxnorm[b], __float_as_int(nrm));  // non-neg floats: int cmp == float cmp
    }
}

// ---------------- fused gather + MLP + maxpool: one block per anchor ----------------
// Weights read directly from global/L2 (no LDS staging).
__global__ __launch_bounds__(256, 6) void mlp_kernel(
    const float* __restrict__ feat, const float* __restrict__ coord,
    const float* __restrict__ anchor_feat, const float* __restrict__ anchor_coord,
    const float* __restrict__ W1, const float* __restrict__ b1,
    const float* __restrict__ g1, const float* __restrict__ be1,
    const float* __restrict__ W2, const float* __restrict__ b2,
    const float* __restrict__ g2, const float* __restrict__ be2,
    const int* __restrict__ maxnorm, const int* __restrict__ idxbuf,
    float* __restrict__ out)
{
    __shared__ __align__(16) float xst[CIN * KNB];   // x transposed: [j][k]
    __shared__ __align__(16) float h1t[H1 * 36];     // h1 transposed: [ch][k], pad to 36
    __shared__ int   sel[KNB];
    __shared__ float pmax[4 * H2];

    const int anchor = blockIdx.x;
    const int b  = anchor >> 11;
    const int mi = anchor & (MM - 1);
    const int tid = threadIdx.x;

    if (tid < KNB) sel[tid] = idxbuf[anchor * KNB + tid];
    __syncthreads();

    const float mn = __int_as_float(maxnorm[b]);

    // build x^T: rows j (3 delta + 64 feat), cols k (neighbors)
    for (int t = tid; t < CIN * KNB; t += 256) {
        int j = t >> 5, k = t & 31;
        int nj = sel[k];
        float vv;
        if (j < 3) {
            float d = __fsub_rn(coord[((size_t)b * NN + nj) * 3 + j],
                                anchor_coord[((size_t)b * MM + mi) * 3 + j]);
            vv = __fdiv_rn(d, mn);
        } else {
            vv = feat[((size_t)b * NN + nj) * CC + (j - 3)]
               - anchor_feat[((size_t)b * MM + mi) * CC + (j - 3)];
        }
        xst[t] = vv;
    }
    __syncthreads();

    const int w = tid >> 6, lane = tid & 63;
    const int k0 = w * 8;   // this wave owns rows k0..k0+7; channel = lane

    // ---- stage 1: h1 = relu(LN(x @ W1 + b1)) ----
    const float bias1 = b1[lane];
    float acc[8];
    #pragma unroll
    for (int kk = 0; kk < 8; kk++) acc[kk] = bias1;
    #pragma unroll 4
    for (int j = 0; j < CIN; j++) {
        float wv = W1[j * H1 + lane];
        const float4 xa = *(const float4*)&xst[j * KNB + k0];
        const float4 xb = *(const float4*)&xst[j * KNB + k0 + 4];
        acc[0] = fmaf(xa.x, wv, acc[0]);
        acc[1] = fmaf(xa.y, wv, acc[1]);
        acc[2] = fmaf(xa.z, wv, acc[2]);
        acc[3] = fmaf(xa.w, wv, acc[3]);
        acc[4] = fmaf(xb.x, wv, acc[4]);
        acc[5] = fmaf(xb.y, wv, acc[5]);
        acc[6] = fmaf(xb.z, wv, acc[6]);
        acc[7] = fmaf(xb.w, wv, acc[7]);
    }
    const float g1v = g1[lane], be1v = be1[lane];
    #pragma unroll
    for (int kk = 0; kk < 8; kk++) {
        float vv = acc[kk];
        float s = vv, s2 = vv * vv;
        #pragma unroll
        for (int off = 32; off; off >>= 1) { s += __shfl_xor(s, off); s2 += __shfl_xor(s2, off); }
        float mu  = s  * (1.0f / H1);
        float var = s2 * (1.0f / H1) - mu * mu;
        float r = rsqrtf(var + 1e-6f);
        float y = fmaf((vv - mu) * r, g1v, be1v);
        h1t[lane * 36 + k0 + kk] = fmaxf(y, 0.0f);
    }
    __syncthreads();

    // ---- stage 2: h2 = relu(LN(h1 @ W2 + b2)), maxpool over k ----
    const float bias2a = b2[lane], bias2b = b2[lane + 64];
    float a[16];
    #pragma unroll
    for (int kk = 0; kk < 8; kk++) { a[kk] = bias2a; a[8 + kk] = bias2b; }
    #pragma unroll 4
    for (int j = 0; j < H1; j++) {
        float w0 = W2[j * H2 + lane];
        float w1 = W2[j * H2 + lane + 64];
        const float4 ha = *(const float4*)&h1t[j * 36 + k0];
        const float4 hb = *(const float4*)&h1t[j * 36 + k0 + 4];
        a[0] = fmaf(ha.x, w0, a[0]);   a[8]  = fmaf(ha.x, w1, a[8]);
        a[1] = fmaf(ha.y, w0, a[1]);   a[9]  = fmaf(ha.y, w1, a[9]);
        a[2] = fmaf(ha.z, w0, a[2]);   a[10] = fmaf(ha.z, w1, a[10]);
        a[3] = fmaf(ha.w, w0, a[3]);   a[11] = fmaf(ha.w, w1, a[11]);
        a[4] = fmaf(hb.x, w0, a[4]);   a[12] = fmaf(hb.x, w1, a[12]);
        a[5] = fmaf(hb.y, w0, a[5]);   a[13] = fmaf(hb.y, w1, a[13]);
        a[6] = fmaf(hb.z, w0, a[6]);   a[14] = fmaf(hb.z, w1, a[14]);
        a[7] = fmaf(hb.w, w0, a[7]);   a[15] = fmaf(hb.w, w1, a[15]);
    }
    const float g2a = g2[lane], g2b = g2[lane + 64];
    const float be2a = be2[lane], be2b = be2[lane + 64];
    float mx0 = -INFINITY, mx1 = -INFINITY;
    #pragma unroll
    for (int kk = 0; kk < 8; kk++) {
        float a0 = a[kk], a1 = a[8 + kk];
        float s = a0 + a1, s2 = a0 * a0 + a1 * a1;
        #pragma unroll
        for (int off = 32; off; off >>= 1) { s += __shfl_xor(s, off); s2 += __shfl_xor(s2, off); }
        float mu  = s  * (1.0f / H2);
        float var = s2 * (1.0f / H2) - mu * mu;
        float r = rsqrtf(var + 1e-6f);
        float y0 = fmaxf(fmaf((a0 - mu) * r, g2a, be2a), 0.0f);
        float y1 = fmaxf(fmaf((a1 - mu) * r, g2b, be2b), 0.0f);
        mx0 = fmaxf(mx0, y0);
        mx1 = fmaxf(mx1, y1);
    }
    pmax[w * H2 + lane]      = mx0;
    pmax[w * H2 + lane + 64] = mx1;
    __syncthreads();
    if (tid < H2) {
        float vv = pmax[tid];
        #pragma unroll
        for (int ww = 1; ww < 4; ww++) vv = fmaxf(vv, pmax[ww * H2 + tid]);
        out[(size_t)anchor * H2 + tid] = vv;
    }
}

extern "C" void kernel_launch(void* const* d_in, const int* in_sizes, int n_in,
                              void* d_out, int out_size, void* d_ws, size_t ws_size,
                              hipStream_t stream) {
    const float* feat         = (const float*)d_in[0];
    const float* coord        = (const float*)d_in[1];
    const float* anchor_feat  = (const float*)d_in[2];
    const float* anchor_coord = (const float*)d_in[3];
    const float* W1  = (const float*)d_in[4];
    const float* b1  = (const float*)d_in[5];
    const float* g1  = (const float*)d_in[6];
    const float* be1 = (const float*)d_in[7];
    const float* W2  = (const float*)d_in[8];
    const float* b2  = (const float*)d_in[9];
    const float* g2  = (const float*)d_in[10];
    const float* be2 = (const float*)d_in[11];
    float* out = (float*)d_out;

    int*   maxn   = (int*)d_ws;                       // 16 ints reserved
    int*   idxbuf = (int*)d_ws + 16;                  // BB*MM*KNB ints
    float* c2buf  = (float*)((int*)d_ws + 16 + BB * MM * KNB);  // BB*NN floats

    init_kernel<<<1, 64, 0, stream>>>(maxn);
    c2_kernel<<<(BB * NN + 255) / 256, 256, 0, stream>>>(coord, c2buf);
    knn_kernel<<<BB * MM, 256, 0, stream>>>(coord, anchor_coord, c2buf, idxbuf, maxn);
    mlp_kernel<<<BB * MM, 256, 0, stream>>>(feat, coord, anchor_feat, anchor_coord,
                                            W1, b1, g1, be1, W2, b2, g2, be2,
                                            maxn, idxbuf, out);
}

// Round 7
// 440.868 us; speedup vs baseline: 1.3264x; 1.3264x over previous
//
#include <hip/hip_runtime.h>
#include <math.h>

#define BB 4
#define NN 8192
#define MM 2048
#define CC 64
#define KNB 32
#define CIN 67   // 3 + CC
#define H1 64
#define H2 128

// ---------------- init: zero per-batch maxnorm cells ----------------
__global__ void init_kernel(int* maxnorm) {
    if (threadIdx.x < BB) maxnorm[threadIdx.x] = 0;
}

// ---------------- c2 precompute: sum of squares per point (validated round 6) ----------------
__global__ __launch_bounds__(256) void c2_kernel(const float* __restrict__ coord,
                                                 float* __restrict__ c2buf) {
    const int t = blockIdx.x * 256 + threadIdx.x;   // t in [0, BB*NN)
    if (t < BB * NN) {
        float cx = coord[t * 3 + 0], cy = coord[t * 3 + 1], cz = coord[t * 3 + 2];
        c2buf[t] = __fadd_rn(__fadd_rn(__fmul_rn(cx, cx), __fmul_rn(cy, cy)), __fmul_rn(cz, cz));
    }
}

// ---------------- kNN: one block per anchor; radix-select (4 passes of 8 bits) ----------------
// Distance phase bit-identical to validated round-1 kernel. Selection: exact
// (d2, idx)-lex top-K via monotone u32 keys + radix rank + smallest-index ties.
__global__ __launch_bounds__(256, 4) void knn_kernel(
    const float* __restrict__ coord, const float* __restrict__ anchor_coord,
    const float* __restrict__ c2buf,
    int* __restrict__ idxbuf, int* __restrict__ maxnorm)
{
    __shared__ unsigned keys[256 * 33];   // padded [chunk][33]; chunk c slot j = point 32c+j
    __shared__ unsigned hist[256];
    __shared__ unsigned segsum[64];
    __shared__ unsigned bc[2];            // [0]=chosen bin, [1]=rank within bin
    __shared__ unsigned nsel;
    __shared__ int      selcell;
    __shared__ int      sel_s[KNB];

    const int anchor = blockIdx.x;
    const int b  = anchor >> 11;          // / MM
    const int mi = anchor & (MM - 1);
    const int tid = threadIdx.x;

    const float ax = anchor_coord[(b * MM + mi) * 3 + 0];
    const float ay = anchor_coord[(b * MM + mi) * 3 + 1];
    const float az = anchor_coord[(b * MM + mi) * 3 + 2];
    const float a2 = __fadd_rn(__fadd_rn(__fmul_rn(ax, ax), __fmul_rn(ay, ay)), __fmul_rn(az, az));

    const float* cb  = coord + (size_t)b * NN * 3;
    const float* c2b = c2buf + (size_t)b * NN;

    // distances (reference formula, bit-identical) -> monotone u32 keys in LDS
    for (int i = tid; i < NN; i += 256) {
        float cx = cb[i * 3 + 0], cy = cb[i * 3 + 1], cz = cb[i * 3 + 2];
        float c2 = c2b[i];
        float dt = __fadd_rn(__fadd_rn(__fmul_rn(ax, cx), __fmul_rn(ay, cy)), __fmul_rn(az, cz));
        float d2 = __fadd_rn(__fsub_rn(a2, __fmul_rn(2.0f, dt)), c2);
        unsigned ub = __float_as_uint(d2);
        ub ^= (unsigned)((int)ub >> 31) | 0x80000000u;   // monotone map: u32 order == float order
        keys[(i >> 5) * 33 + (i & 31)] = ub;
    }
    hist[tid] = 0;
    __syncthreads();

    const int base = tid * 33;            // this thread scans chunk tid = points 32*tid..32*tid+31
    unsigned prefix = 0, pmask = 0;
    unsigned k = KNB;                     // rank sought (1-indexed) among candidates matching prefix

    #pragma unroll
    for (int pass = 0; pass < 4; pass++) {
        const int sh = 24 - 8 * pass;
        // parallel histogram of candidates matching established prefix
        #pragma unroll 8
        for (int j = 0; j < 32; j++) {
            unsigned kk = keys[base + j];
            if ((kk & pmask) == prefix) atomicAdd(&hist[(kk >> sh) & 0xFFu], 1u);
        }
        __syncthreads();
        if (tid < 64) {
            segsum[tid] = hist[4 * tid] + hist[4 * tid + 1] + hist[4 * tid + 2] + hist[4 * tid + 3];
        }
        __syncthreads();
        if (tid == 0) {
            unsigned cum = 0; int seg = 0;
            for (; seg < 63; seg++) { unsigned s = segsum[seg]; if (cum + s >= k) break; cum += s; }
            int bin = 4 * seg;
            for (;; bin++) { unsigned h = hist[bin]; if (cum + h >= k) break; cum += h; }
            bc[0] = (unsigned)bin;
            bc[1] = k - cum;
        }
        __syncthreads();
        prefix |= bc[0] << sh;
        pmask  |= 0xFFu << sh;
        k = bc[1];
        hist[tid] = 0;                    // re-zero for next pass
        if (tid == 0) nsel = 0;
        __syncthreads();
    }
    const unsigned T = prefix;            // exact key of the 32nd-smallest element

    // emission: all keys < T (order within set irrelevant downstream)
    unsigned tiemask = 0;
    #pragma unroll 8
    for (int j = 0; j < 32; j++) {
        unsigned kk = keys[base + j];
        if (kk < T) { unsigned pos = atomicAdd(&nsel, 1u); sel_s[pos] = tid * 32 + j; }
        else if (kk == T) tiemask |= 1u << j;
    }
    __syncthreads();
    const unsigned n_lt = nsel;           // < KNB by construction
    const unsigned needed = KNB - n_lt;   // >= 1; ties taken in increasing index order
    int last = -1;
    for (unsigned r = 0; r < needed; r++) {
        if (tid == 0) selcell = 0x7fffffff;
        __syncthreads();
        unsigned m = tiemask;
        while (m) {
            int j = __ffs(m) - 1; m &= m - 1;
            int idx = tid * 32 + j;
            if (idx > last) atomicMin(&selcell, idx);
        }
        __syncthreads();
        last = selcell;
        if (tid == 0) sel_s[n_lt + r] = last;
        __syncthreads();
    }

    // write indices; per-batch max ||delta|| (validated round-1 code)
    float nrm = 0.0f;
    if (tid < KNB) {
        int j = sel_s[tid];
        idxbuf[anchor * KNB + tid] = j;
        float dx = __fsub_rn(cb[j * 3 + 0], ax);
        float dy = __fsub_rn(cb[j * 3 + 1], ay);
        float dz = __fsub_rn(cb[j * 3 + 2], az);
        nrm = sqrtf(dx * dx + dy * dy + dz * dz);
    }
    if (tid < 64) {
        #pragma unroll
        for (int off = 32; off; off >>= 1) nrm = fmaxf(nrm, __shfl_xor(nrm, off));
        if (tid == 0) atomicMax(&maxnorm[b], __float_as_int(nrm));  // non-neg floats: int cmp == float cmp
    }
}

// ---------------- fused gather + MLP + maxpool: one block per anchor ----------------
// Weights read directly from global/L2 (no LDS staging). Validated round 5.
__global__ __launch_bounds__(256, 6) void mlp_kernel(
    const float* __restrict__ feat, const float* __restrict__ coord,
    const float* __restrict__ anchor_feat, const float* __restrict__ anchor_coord,
    const float* __restrict__ W1, const float* __restrict__ b1,
    const float* __restrict__ g1, const float* __restrict__ be1,
    const float* __restrict__ W2, const float* __restrict__ b2,
    const float* __restrict__ g2, const float* __restrict__ be2,
    const int* __restrict__ maxnorm, const int* __restrict__ idxbuf,
    float* __restrict__ out)
{
    __shared__ __align__(16) float xst[CIN * KNB];   // x transposed: [j][k]
    __shared__ __align__(16) float h1t[H1 * 36];     // h1 transposed: [ch][k], pad to 36
    __shared__ int   sel[KNB];
    __shared__ float pmax[4 * H2];

    const int anchor = blockIdx.x;
    const int b  = anchor >> 11;
    const int mi = anchor & (MM - 1);
    const int tid = threadIdx.x;

    if (tid < KNB) sel[tid] = idxbuf[anchor * KNB + tid];
    __syncthreads();

    const float mn = __int_as_float(maxnorm[b]);

    // build x^T: rows j (3 delta + 64 feat), cols k (neighbors)
    for (int t = tid; t < CIN * KNB; t += 256) {
        int j = t >> 5, k = t & 31;
        int nj = sel[k];
        float vv;
        if (j < 3) {
            float d = __fsub_rn(coord[((size_t)b * NN + nj) * 3 + j],
                                anchor_coord[((size_t)b * MM + mi) * 3 + j]);
            vv = __fdiv_rn(d, mn);
        } else {
            vv = feat[((size_t)b * NN + nj) * CC + (j - 3)]
               - anchor_feat[((size_t)b * MM + mi) * CC + (j - 3)];
        }
        xst[t] = vv;
    }
    __syncthreads();

    const int w = tid >> 6, lane = tid & 63;
    const int k0 = w * 8;   // this wave owns rows k0..k0+7; channel = lane

    // ---- stage 1: h1 = relu(LN(x @ W1 + b1)) ----
    const float bias1 = b1[lane];
    float acc[8];
    #pragma unroll
    for (int kk = 0; kk < 8; kk++) acc[kk] = bias1;
    #pragma unroll 4
    for (int j = 0; j < CIN; j++) {
        float wv = W1[j * H1 + lane];
        const float4 xa = *(const float4*)&xst[j * KNB + k0];
        const float4 xb = *(const float4*)&xst[j * KNB + k0 + 4];
        acc[0] = fmaf(xa.x, wv, acc[0]);
        acc[1] = fmaf(xa.y, wv, acc[1]);
        acc[2] = fmaf(xa.z, wv, acc[2]);
        acc[3] = fmaf(xa.w, wv, acc[3]);
        acc[4] = fmaf(xb.x, wv, acc[4]);
        acc[5] = fmaf(xb.y, wv, acc[5]);
        acc[6] = fmaf(xb.z, wv, acc[6]);
        acc[7] = fmaf(xb.w, wv, acc[7]);
    }
    const float g1v = g1[lane], be1v = be1[lane];
    #pragma unroll
    for (int kk = 0; kk < 8; kk++) {
        float vv = acc[kk];
        float s = vv, s2 = vv * vv;
        #pragma unroll
        for (int off = 32; off; off >>= 1) { s += __shfl_xor(s, off); s2 += __shfl_xor(s2, off); }
        float mu  = s  * (1.0f / H1);
        float var = s2 * (1.0f / H1) - mu * mu;
        float r = rsqrtf(var + 1e-6f);
        float y = fmaf((vv - mu) * r, g1v, be1v);
        h1t[lane * 36 + k0 + kk] = fmaxf(y, 0.0f);
    }
    __syncthreads();

    // ---- stage 2: h2 = relu(LN(h1 @ W2 + b2)), maxpool over k ----
    const float bias2a = b2[lane], bias2b = b2[lane + 64];
    float a[16];
    #pragma unroll
    for (int kk = 0; kk < 8; kk++) { a[kk] = bias2a; a[8 + kk] = bias2b; }
    #pragma unroll 4
    for (int j = 0; j < H1; j++) {
        float w0 = W2[j * H2 + lane];
        float w1 = W2[j * H2 + lane + 64];
        const float4 ha = *(const float4*)&h1t[j * 36 + k0];
        const float4 hb = *(const float4*)&h1t[j * 36 + k0 + 4];
        a[0] = fmaf(ha.x, w0, a[0]);   a[8]  = fmaf(ha.x, w1, a[8]);
        a[1] = fmaf(ha.y, w0, a[1]);   a[9]  = fmaf(ha.y, w1, a[9]);
        a[2] = fmaf(ha.z, w0, a[2]);   a[10] = fmaf(ha.z, w1, a[10]);
        a[3] = fmaf(ha.w, w0, a[3]);   a[11] = fmaf(ha.w, w1, a[11]);
        a[4] = fmaf(hb.x, w0, a[4]);   a[12] = fmaf(hb.x, w1, a[12]);
        a[5] = fmaf(hb.y, w0, a[5]);   a[13] = fmaf(hb.y, w1, a[13]);
        a[6] = fmaf(hb.z, w0, a[6]);   a[14] = fmaf(hb.z, w1, a[14]);
        a[7] = fmaf(hb.w, w0, a[7]);   a[15] = fmaf(hb.w, w1, a[15]);
    }
    const float g2a = g2[lane], g2b = g2[lane + 64];
    const float be2a = be2[lane], be2b = be2[lane + 64];
    float mx0 = -INFINITY, mx1 = -INFINITY;
    #pragma unroll
    for (int kk = 0; kk < 8; kk++) {
        float a0 = a[kk], a1 = a[8 + kk];
        float s = a0 + a1, s2 = a0 * a0 + a1 * a1;
        #pragma unroll
        for (int off = 32; off; off >>= 1) { s += __shfl_xor(s, off); s2 += __shfl_xor(s2, off); }
        float mu  = s  * (1.0f / H2);
        float var = s2 * (1.0f / H2) - mu * mu;
        float r = rsqrtf(var + 1e-6f);
        float y0 = fmaxf(fmaf((a0 - mu) * r, g2a, be2a), 0.0f);
        float y1 = fmaxf(fmaf((a1 - mu) * r, g2b, be2b), 0.0f);
        mx0 = fmaxf(mx0, y0);
        mx1 = fmaxf(mx1, y1);
    }
    pmax[w * H2 + lane]      = mx0;
    pmax[w * H2 + lane + 64] = mx1;
    __syncthreads();
    if (tid < H2) {
        float vv = pmax[tid];
        #pragma unroll
        for (int ww = 1; ww < 4; ww++) vv = fmaxf(vv, pmax[ww * H2 + tid]);
        out[(size_t)anchor * H2 + tid] = vv;
    }
}

extern "C" void kernel_launch(void* const* d_in, const int* in_sizes, int n_in,
                              void* d_out, int out_size, void* d_ws, size_t ws_size,
                              hipStream_t stream) {
    const float* feat         = (const float*)d_in[0];
    const float* coord        = (const float*)d_in[1];
    const float* anchor_feat  = (const float*)d_in[2];
    const float* anchor_coord = (const float*)d_in[3];
    const float* W1  = (const float*)d_in[4];
    const float* b1  = (const float*)d_in[5];
    const float* g1  = (const float*)d_in[6];
    const float* be1 = (const float*)d_in[7];
    const float* W2  = (const float*)d_in[8];
    const float* b2  = (const float*)d_in[9];
    const float* g2  = (const float*)d_in[10];
    const float* be2 = (const float*)d_in[11];
    float* out = (float*)d_out;

    int*   maxn   = (int*)d_ws;                       // 16 ints reserved
    int*   idxbuf = (int*)d_ws + 16;                  // BB*MM*KNB ints
    float* c2buf  = (float*)((int*)d_ws + 16 + BB * MM * KNB);  // BB*NN floats

    init_kernel<<<1, 64, 0, stream>>>(maxn);
    c2_kernel<<<(BB * NN + 255) / 256, 256, 0, stream>>>(coord, c2buf);
    knn_kernel<<<BB * MM, 256, 0, stream>>>(coord, anchor_coord, c2buf, idxbuf, maxn);
    mlp_kernel<<<BB * MM, 256, 0, stream>>>(feat, coord, anchor_feat, anchor_coord,
                                            W1, b1, g1, be1, W2, b2, g2, be2,
                                            maxn, idxbuf, out);
}

// Round 8
// 337.129 us; speedup vs baseline: 1.7345x; 1.3077x over previous
//
#include <hip/hip_runtime.h>
#include <math.h>

#define BB 4
#define NN 8192
#define MM 2048
#define CC 64
#define KNB 32
#define CIN 67   // 3 + CC
#define H1 64
#define H2 128

// ---------------- init: zero per-batch maxnorm cells ----------------
__global__ void init_kernel(int* maxnorm) {
    if (threadIdx.x < BB) maxnorm[threadIdx.x] = 0;
}

// ---------------- c2 precompute: sum of squares per point (validated round 6) ----------------
__global__ __launch_bounds__(256) void c2_kernel(const float* __restrict__ coord,
                                                 float* __restrict__ c2buf) {
    const int t = blockIdx.x * 256 + threadIdx.x;   // t in [0, BB*NN)
    if (t < BB * NN) {
        float cx = coord[t * 3 + 0], cy = coord[t * 3 + 1], cz = coord[t * 3 + 2];
        c2buf[t] = __fadd_rn(__fadd_rn(__fmul_rn(cx, cx), __fmul_rn(cy, cy)), __fmul_rn(cz, cz));
    }
}

// ---------------- kNN: one block per anchor; register-resident radix select ----------------
// Same exact selection math as validated round 7 (monotone u32 keys, 4x8-bit radix
// rank, <T emission + lowest-index tie rounds). Keys in VGPRs; pass-0 histogram
// fused into distance loop; parallel prefix-scan bin selection (no serial scans).
__global__ __launch_bounds__(256, 4) void knn_kernel(
    const float* __restrict__ coord, const float* __restrict__ anchor_coord,
    const float* __restrict__ c2buf,
    int* __restrict__ idxbuf, int* __restrict__ maxnorm)
{
    __shared__ unsigned hist[256];
    __shared__ unsigned wtot[4];
    __shared__ unsigned bc[2];            // [0]=chosen bin, [1]=rank within bin
    __shared__ unsigned nsel;
    __shared__ int      selcell;
    __shared__ int      sel_s[KNB];

    const int anchor = blockIdx.x;
    const int b  = anchor >> 11;          // / MM
    const int mi = anchor & (MM - 1);
    const int tid = threadIdx.x;
    const int w = tid >> 6, lane = tid & 63;

    const float ax = anchor_coord[(b * MM + mi) * 3 + 0];
    const float ay = anchor_coord[(b * MM + mi) * 3 + 1];
    const float az = anchor_coord[(b * MM + mi) * 3 + 2];
    const float a2 = __fadd_rn(__fadd_rn(__fmul_rn(ax, ax), __fmul_rn(ay, ay)), __fmul_rn(az, az));

    const float* cb  = coord + (size_t)b * NN * 3;
    const float* c2b = c2buf + (size_t)b * NN;

    hist[tid] = 0;
    if (tid == 0) nsel = 0;
    __syncthreads();

    // distances (reference formula, bit-identical) -> monotone keys in REGISTERS;
    // pass-0 histogram built on the fly (atomics hide under load latency)
    unsigned kreg[32];
    #pragma unroll
    for (int j = 0; j < 32; j++) {
        const int i = tid + 256 * j;      // thread's points: strided, idx = tid + 256*j
        float cx = cb[i * 3 + 0], cy = cb[i * 3 + 1], cz = cb[i * 3 + 2];
        float c2 = c2b[i];
        float dt = __fadd_rn(__fadd_rn(__fmul_rn(ax, cx), __fmul_rn(ay, cy)), __fmul_rn(az, cz));
        float d2 = __fadd_rn(__fsub_rn(a2, __fmul_rn(2.0f, dt)), c2);
        unsigned ub = __float_as_uint(d2);
        ub ^= (unsigned)((int)ub >> 31) | 0x80000000u;   // monotone: u32 order == float order
        kreg[j] = ub;
        atomicAdd(&hist[ub >> 24], 1u);
    }
    __syncthreads();

    unsigned prefix = 0, pmask = 0;
    unsigned k = KNB;                     // rank sought (1-indexed) among prefix-matching keys

    #pragma unroll
    for (int pass = 0; pass < 4; pass++) {
        const int sh = 24 - 8 * pass;
        if (pass > 0) {
            hist[tid] = 0;
            __syncthreads();
            #pragma unroll
            for (int j = 0; j < 32; j++) {
                unsigned kk = kreg[j];
                if ((kk & pmask) == prefix) atomicAdd(&hist[(kk >> sh) & 0xFFu], 1u);
            }
            __syncthreads();
        }
        // parallel bin selection: thread tid owns bin tid
        const unsigned h = hist[tid];
        unsigned v = h;
        #pragma unroll
        for (int d = 1; d < 64; d <<= 1) {
            unsigned t = __shfl_up(v, d);
            if (lane >= d) v += t;
        }
        if (lane == 63) wtot[w] = v;
        __syncthreads();
        unsigned off = 0;
        #pragma unroll
        for (int ww = 0; ww < 3; ww++) if (ww < w) off += wtot[ww];
        v += off;                          // inclusive prefix over bins 0..tid
        const unsigned excl = v - h;
        if (excl < k && k <= v) { bc[0] = (unsigned)tid; bc[1] = k - excl; }  // unique bin
        __syncthreads();
        prefix |= bc[0] << sh;
        pmask  |= 0xFFu << sh;
        k = bc[1];
        // safe: next write to bc is 2 barriers away (hist zero + atomics)
    }
    const unsigned T = prefix;            // exact key of the 32nd-smallest element

    // emission: all keys < T (set order irrelevant downstream)
    unsigned tiemask = 0;
    #pragma unroll
    for (int j = 0; j < 32; j++) {
        unsigned kk = kreg[j];
        if (kk < T) { unsigned pos = atomicAdd(&nsel, 1u); sel_s[pos] = tid + 256 * j; }
        else if (kk == T) tiemask |= 1u << j;
    }
    __syncthreads();
    const unsigned n_lt = nsel;           // < KNB by construction
    const unsigned needed = KNB - n_lt;   // >= 1; ties taken in increasing index order
    int last = -1;
    for (unsigned r = 0; r < needed; r++) {
        if (tid == 0) selcell = 0x7fffffff;
        __syncthreads();
        unsigned m = tiemask;
        while (m) {
            int j = __ffs(m) - 1; m &= m - 1;
            int idx = tid + 256 * j;
            if (idx > last) atomicMin(&selcell, idx);
        }
        __syncthreads();
        last = selcell;
        if (tid == 0) sel_s[n_lt + r] = last;
        __syncthreads();
    }

    // write indices; per-batch max ||delta|| (validated round-1 code)
    float nrm = 0.0f;
    if (tid < KNB) {
        int j = sel_s[tid];
        idxbuf[anchor * KNB + tid] = j;
        float dx = __fsub_rn(cb[j * 3 + 0], ax);
        float dy = __fsub_rn(cb[j * 3 + 1], ay);
        float dz = __fsub_rn(cb[j * 3 + 2], az);
        nrm = sqrtf(dx * dx + dy * dy + dz * dz);
    }
    if (tid < 64) {
        #pragma unroll
        for (int off = 32; off; off >>= 1) nrm = fmaxf(nrm, __shfl_xor(nrm, off));
        if (tid == 0) atomicMax(&maxnorm[b], __float_as_int(nrm));  // non-neg floats: int cmp == float cmp
    }
}

// ---------------- fused gather + MLP + maxpool: one block per anchor ----------------
// Weights read directly from global/L2 (no LDS staging). Validated round 5.
__global__ __launch_bounds__(256, 6) void mlp_kernel(
    const float* __restrict__ feat, const float* __restrict__ coord,
    const float* __restrict__ anchor_feat, const float* __restrict__ anchor_coord,
    const float* __restrict__ W1, const float* __restrict__ b1,
    const float* __restrict__ g1, const float* __restrict__ be1,
    const float* __restrict__ W2, const float* __restrict__ b2,
    const float* __restrict__ g2, const float* __restrict__ be2,
    const int* __restrict__ maxnorm, const int* __restrict__ idxbuf,
    float* __restrict__ out)
{
    __shared__ __align__(16) float xst[CIN * KNB];   // x transposed: [j][k]
    __shared__ __align__(16) float h1t[H1 * 36];     // h1 transposed: [ch][k], pad to 36
    __shared__ int   sel[KNB];
    __shared__ float pmax[4 * H2];

    const int anchor = blockIdx.x;
    const int b  = anchor >> 11;
    const int mi = anchor & (MM - 1);
    const int tid = threadIdx.x;

    if (tid < KNB) sel[tid] = idxbuf[anchor * KNB + tid];
    __syncthreads();

    const float mn = __int_as_float(maxnorm[b]);

    // build x^T: rows j (3 delta + 64 feat), cols k (neighbors)
    for (int t = tid; t < CIN * KNB; t += 256) {
        int j = t >> 5, k = t & 31;
        int nj = sel[k];
        float vv;
        if (j < 3) {
            float d = __fsub_rn(coord[((size_t)b * NN + nj) * 3 + j],
                                anchor_coord[((size_t)b * MM + mi) * 3 + j]);
            vv = __fdiv_rn(d, mn);
        } else {
            vv = feat[((size_t)b * NN + nj) * CC + (j - 3)]
               - anchor_feat[((size_t)b * MM + mi) * CC + (j - 3)];
        }
        xst[t] = vv;
    }
    __syncthreads();

    const int w = tid >> 6, lane = tid & 63;
    const int k0 = w * 8;   // this wave owns rows k0..k0+7; channel = lane

    // ---- stage 1: h1 = relu(LN(x @ W1 + b1)) ----
    const float bias1 = b1[lane];
    float acc[8];
    #pragma unroll
    for (int kk = 0; kk < 8; kk++) acc[kk] = bias1;
    #pragma unroll 4
    for (int j = 0; j < CIN; j++) {
        float wv = W1[j * H1 + lane];
        const float4 xa = *(const float4*)&xst[j * KNB + k0];
        const float4 xb = *(const float4*)&xst[j * KNB + k0 + 4];
        acc[0] = fmaf(xa.x, wv, acc[0]);
        acc[1] = fmaf(xa.y, wv, acc[1]);
        acc[2] = fmaf(xa.z, wv, acc[2]);
        acc[3] = fmaf(xa.w, wv, acc[3]);
        acc[4] = fmaf(xb.x, wv, acc[4]);
        acc[5] = fmaf(xb.y, wv, acc[5]);
        acc[6] = fmaf(xb.z, wv, acc[6]);
        acc[7] = fmaf(xb.w, wv, acc[7]);
    }
    const float g1v = g1[lane], be1v = be1[lane];
    #pragma unroll
    for (int kk = 0; kk < 8; kk++) {
        float vv = acc[kk];
        float s = vv, s2 = vv * vv;
        #pragma unroll
        for (int off = 32; off; off >>= 1) { s += __shfl_xor(s, off); s2 += __shfl_xor(s2, off); }
        float mu  = s  * (1.0f / H1);
        float var = s2 * (1.0f / H1) - mu * mu;
        float r = rsqrtf(var + 1e-6f);
        float y = fmaf((vv - mu) * r, g1v, be1v);
        h1t[lane * 36 + k0 + kk] = fmaxf(y, 0.0f);
    }
    __syncthreads();

    // ---- stage 2: h2 = relu(LN(h1 @ W2 + b2)), maxpool over k ----
    const float bias2a = b2[lane], bias2b = b2[lane + 64];
    float a[16];
    #pragma unroll
    for (int kk = 0; kk < 8; kk++) { a[kk] = bias2a; a[8 + kk] = bias2b; }
    #pragma unroll 4
    for (int j = 0; j < H1; j++) {
        float w0 = W2[j * H2 + lane];
        float w1 = W2[j * H2 + lane + 64];
        const float4 ha = *(const float4*)&h1t[j * 36 + k0];
        const float4 hb = *(const float4*)&h1t[j * 36 + k0 + 4];
        a[0] = fmaf(ha.x, w0, a[0]);   a[8]  = fmaf(ha.x, w1, a[8]);
        a[1] = fmaf(ha.y, w0, a[1]);   a[9]  = fmaf(ha.y, w1, a[9]);
        a[2] = fmaf(ha.z, w0, a[2]);   a[10] = fmaf(ha.z, w1, a[10]);
        a[3] = fmaf(ha.w, w0, a[3]);   a[11] = fmaf(ha.w, w1, a[11]);
        a[4] = fmaf(hb.x, w0, a[4]);   a[12] = fmaf(hb.x, w1, a[12]);
        a[5] = fmaf(hb.y, w0, a[5]);   a[13] = fmaf(hb.y, w1, a[13]);
        a[6] = fmaf(hb.z, w0, a[6]);   a[14] = fmaf(hb.z, w1, a[14]);
        a[7] = fmaf(hb.w, w0, a[7]);   a[15] = fmaf(hb.w, w1, a[15]);
    }
    const float g2a = g2[lane], g2b = g2[lane + 64];
    const float be2a = be2[lane], be2b = be2[lane + 64];
    float mx0 = -INFINITY, mx1 = -INFINITY;
    #pragma unroll
    for (int kk = 0; kk < 8; kk++) {
        float a0 = a[kk], a1 = a[8 + kk];
        float s = a0 + a1, s2 = a0 * a0 + a1 * a1;
        #pragma unroll
        for (int off = 32; off; off >>= 1) { s += __shfl_xor(s, off); s2 += __shfl_xor(s2, off); }
        float mu  = s  * (1.0f / H2);
        float var = s2 * (1.0f / H2) - mu * mu;
        float r = rsqrtf(var + 1e-6f);
        float y0 = fmaxf(fmaf((a0 - mu) * r, g2a, be2a), 0.0f);
        float y1 = fmaxf(fmaf((a1 - mu) * r, g2b, be2b), 0.0f);
        mx0 = fmaxf(mx0, y0);
        mx1 = fmaxf(mx1, y1);
    }
    pmax[w * H2 + lane]      = mx0;
    pmax[w * H2 + lane + 64] = mx1;
    __syncthreads();
    if (tid < H2) {
        float vv = pmax[tid];
        #pragma unroll
        for (int ww = 1; ww < 4; ww++) vv = fmaxf(vv, pmax[ww * H2 + tid]);
        out[(size_t)anchor * H2 + tid] = vv;
    }
}

extern "C" void kernel_launch(void* const* d_in, const int* in_sizes, int n_in,
                              void* d_out, int out_size, void* d_ws, size_t ws_size,
                              hipStream_t stream) {
    const float* feat         = (const float*)d_in[0];
    const float* coord        = (const float*)d_in[1];
    const float* anchor_feat  = (const float*)d_in[2];
    const float* anchor_coord = (const float*)d_in[3];
    const float* W1  = (const float*)d_in[4];
    const float* b1  = (const float*)d_in[5];
    const float* g1  = (const float*)d_in[6];
    const float* be1 = (const float*)d_in[7];
    const float* W2  = (const float*)d_in[8];
    const float* b2  = (const float*)d_in[9];
    const float* g2  = (const float*)d_in[10];
    const float* be2 = (const float*)d_in[11];
    float* out = (float*)d_out;

    int*   maxn   = (int*)d_ws;                       // 16 ints reserved
    int*   idxbuf = (int*)d_ws + 16;                  // BB*MM*KNB ints
    float* c2buf  = (float*)((int*)d_ws + 16 + BB * MM * KNB);  // BB*NN floats

    init_kernel<<<1, 64, 0, stream>>>(maxn);
    c2_kernel<<<(BB * NN + 255) / 256, 256, 0, stream>>>(coord, c2buf);
    knn_kernel<<<BB * MM, 256, 0, stream>>>(coord, anchor_coord, c2buf, idxbuf, maxn);
    mlp_kernel<<<BB * MM, 256, 0, stream>>>(feat, coord, anchor_feat, anchor_coord,
                                            W1, b1, g1, be1, W2, b2, g2, be2,
                                            maxn, idxbuf, out);
}

// Round 9
// 275.178 us; speedup vs baseline: 2.1250x; 1.2251x over previous
//
#include <hip/hip_runtime.h>
#include <math.h>

#define BB 4
#define NN 8192
#define MM 2048
#define CC 64
#define KNB 32
#define CIN 67   // 3 + CC
#define H1 64
#define H2 128

// ---------------- init: zero per-batch maxnorm cells ----------------
__global__ void init_kernel(int* maxnorm) {
    if (threadIdx.x < BB) maxnorm[threadIdx.x] = 0;
}

// ---------------- c2 precompute: sum of squares per point (validated round 6) ----------------
__global__ __launch_bounds__(256) void c2_kernel(const float* __restrict__ coord,
                                                 float* __restrict__ c2buf) {
    const int t = blockIdx.x * 256 + threadIdx.x;   // t in [0, BB*NN)
    if (t < BB * NN) {
        float cx = coord[t * 3 + 0], cy = coord[t * 3 + 1], cz = coord[t * 3 + 2];
        c2buf[t] = __fadd_rn(__fadd_rn(__fmul_rn(cx, cx), __fmul_rn(cy, cy)), __fmul_rn(cz, cz));
    }
}

// ---------------- kNN: one block per anchor; register radix select + U-prefilter ----------------
// Selection math identical to validated round 8 (monotone u32 keys, 4x8-bit radix
// rank, <T emission + lowest-index ties). New: (a) upper bound U on T (max of 32
// designated per-thread minima; >=32 keys <= U ensures every histogram the radix
// walk consults is complete where it matters -> exactness preserved), so only
// ~10% of keys hit the histogram atomics; (b) per-wave histogram copies kill
// cross-wave same-bin serialization.
__global__ __launch_bounds__(256, 4) void knn_kernel(
    const float* __restrict__ coord, const float* __restrict__ anchor_coord,
    const float* __restrict__ c2buf,
    int* __restrict__ idxbuf, int* __restrict__ maxnorm)
{
    __shared__ unsigned hist[4][256];     // per-wave histogram copies
    __shared__ unsigned wmax[4];
    __shared__ unsigned wtot[4];
    __shared__ unsigned bc[2];            // [0]=chosen bin, [1]=rank within bin
    __shared__ unsigned nsel;
    __shared__ int      selcell;
    __shared__ int      sel_s[KNB];

    const int anchor = blockIdx.x;
    const int b  = anchor >> 11;          // / MM
    const int mi = anchor & (MM - 1);
    const int tid = threadIdx.x;
    const int w = tid >> 6, lane = tid & 63;

    const float ax = anchor_coord[(b * MM + mi) * 3 + 0];
    const float ay = anchor_coord[(b * MM + mi) * 3 + 1];
    const float az = anchor_coord[(b * MM + mi) * 3 + 2];
    const float a2 = __fadd_rn(__fadd_rn(__fmul_rn(ax, ax), __fmul_rn(ay, ay)), __fmul_rn(az, az));

    const float* cb  = coord + (size_t)b * NN * 3;
    const float* c2b = c2buf + (size_t)b * NN;

    // distances (reference formula, bit-identical) -> monotone keys in REGISTERS
    unsigned kreg[32];
    unsigned tmin = 0xFFFFFFFFu;
    #pragma unroll
    for (int j = 0; j < 32; j++) {
        const int i = tid + 256 * j;      // thread's points: idx = tid + 256*j
        float cx = cb[i * 3 + 0], cy = cb[i * 3 + 1], cz = cb[i * 3 + 2];
        float c2 = c2b[i];
        float dt = __fadd_rn(__fadd_rn(__fmul_rn(ax, cx), __fmul_rn(ay, cy)), __fmul_rn(az, cz));
        float d2 = __fadd_rn(__fsub_rn(a2, __fmul_rn(2.0f, dt)), c2);
        unsigned ub = __float_as_uint(d2);
        ub ^= (unsigned)((int)ub >> 31) | 0x80000000u;   // monotone: u32 order == float order
        kreg[j] = ub;
        tmin = tmin < ub ? tmin : ub;
    }

    // U = max over 32 designated per-thread minima (lanes 0..7 of each wave).
    // Each of those 32 threads holds >=1 key <= its min <= U  =>  >=32 keys <= U  =>  T <= U.
    unsigned um = tmin;
    um = max(um, (unsigned)__shfl_xor((int)um, 1));
    um = max(um, (unsigned)__shfl_xor((int)um, 2));
    um = max(um, (unsigned)__shfl_xor((int)um, 4));   // lanes 0..7 now hold max over their group
    if (lane == 0) wmax[w] = um;
    if (tid == 0) nsel = 0;
    __syncthreads();
    const unsigned U = max(max(wmax[0], wmax[1]), max(wmax[2], wmax[3]));

    unsigned prefix = 0, pmask = 0;
    unsigned k = KNB;                     // rank sought (1-indexed) among prefix-matching keys

    #pragma unroll
    for (int pass = 0; pass < 4; pass++) {
        const int sh = 24 - 8 * pass;
        // zero all 4 hist copies (flat view)
        unsigned* hf = &hist[0][0];
        hf[tid] = 0; hf[tid + 256] = 0; hf[tid + 512] = 0; hf[tid + 768] = 0;
        __syncthreads();
        #pragma unroll
        for (int j = 0; j < 32; j++) {
            unsigned kk = kreg[j];
            if (kk <= U && (kk & pmask) == prefix) atomicAdd(&hist[w][(kk >> sh) & 0xFFu], 1u);
        }
        __syncthreads();
        // parallel bin selection: thread tid owns bin tid (sum of 4 wave copies)
        const unsigned h = hist[0][tid] + hist[1][tid] + hist[2][tid] + hist[3][tid];
        unsigned v = h;
        #pragma unroll
        for (int d = 1; d < 64; d <<= 1) {
            unsigned t = __shfl_up(v, d);
            if (lane >= d) v += t;
        }
        if (lane == 63) wtot[w] = v;
        __syncthreads();
        unsigned off = 0;
        #pragma unroll
        for (int ww = 0; ww < 3; ww++) if (ww < w) off += wtot[ww];
        v += off;                          // inclusive prefix over bins 0..tid
        const unsigned excl = v - h;
        if (excl < k && k <= v) { bc[0] = (unsigned)tid; bc[1] = k - excl; }  // unique bin
        __syncthreads();
        prefix |= bc[0] << sh;
        pmask  |= 0xFFu << sh;
        k = bc[1];
        // safe: next write to bc is 2 barriers away (hist zero + atomics)
    }
    const unsigned T = prefix;            // exact key of the 32nd-smallest element

    // emission: all keys < T (set order irrelevant downstream)
    unsigned tiemask = 0;
    #pragma unroll
    for (int j = 0; j < 32; j++) {
        unsigned kk = kreg[j];
        if (kk < T) { unsigned pos = atomicAdd(&nsel, 1u); sel_s[pos] = tid + 256 * j; }
        else if (kk == T) tiemask |= 1u << j;
    }
    __syncthreads();
    const unsigned n_lt = nsel;           // < KNB by construction
    const unsigned needed = KNB - n_lt;   // >= 1; ties taken in increasing index order
    int last = -1;
    for (unsigned r = 0; r < needed; r++) {
        if (tid == 0) selcell = 0x7fffffff;
        __syncthreads();
        unsigned m = tiemask;
        while (m) {
            int j = __ffs(m) - 1; m &= m - 1;
            int idx = tid + 256 * j;
            if (idx > last) atomicMin(&selcell, idx);
        }
        __syncthreads();
        last = selcell;
        if (tid == 0) sel_s[n_lt + r] = last;
        __syncthreads();
    }

    // write indices; per-batch max ||delta|| (validated round-1 code)
    float nrm = 0.0f;
    if (tid < KNB) {
        int j = sel_s[tid];
        idxbuf[anchor * KNB + tid] = j;
        float dx = __fsub_rn(cb[j * 3 + 0], ax);
        float dy = __fsub_rn(cb[j * 3 + 1], ay);
        float dz = __fsub_rn(cb[j * 3 + 2], az);
        nrm = sqrtf(dx * dx + dy * dy + dz * dz);
    }
    if (tid < 64) {
        #pragma unroll
        for (int off = 32; off; off >>= 1) nrm = fmaxf(nrm, __shfl_xor(nrm, off));
        if (tid == 0) atomicMax(&maxnorm[b], __float_as_int(nrm));  // non-neg floats: int cmp == float cmp
    }
}

// ---------------- fused gather + MLP + maxpool: one block per anchor ----------------
// Weights read directly from global/L2 (no LDS staging). Validated round 5.
__global__ __launch_bounds__(256, 6) void mlp_kernel(
    const float* __restrict__ feat, const float* __restrict__ coord,
    const float* __restrict__ anchor_feat, const float* __restrict__ anchor_coord,
    const float* __restrict__ W1, const float* __restrict__ b1,
    const float* __restrict__ g1, const float* __restrict__ be1,
    const float* __restrict__ W2, const float* __restrict__ b2,
    const float* __restrict__ g2, const float* __restrict__ be2,
    const int* __restrict__ maxnorm, const int* __restrict__ idxbuf,
    float* __restrict__ out)
{
    __shared__ __align__(16) float xst[CIN * KNB];   // x transposed: [j][k]
    __shared__ __align__(16) float h1t[H1 * 36];     // h1 transposed: [ch][k], pad to 36
    __shared__ int   sel[KNB];
    __shared__ float pmax[4 * H2];

    const int anchor = blockIdx.x;
    const int b  = anchor >> 11;
    const int mi = anchor & (MM - 1);
    const int tid = threadIdx.x;

    if (tid < KNB) sel[tid] = idxbuf[anchor * KNB + tid];
    __syncthreads();

    const float mn = __int_as_float(maxnorm[b]);

    // build x^T: rows j (3 delta + 64 feat), cols k (neighbors)
    for (int t = tid; t < CIN * KNB; t += 256) {
        int j = t >> 5, k = t & 31;
        int nj = sel[k];
        float vv;
        if (j < 3) {
            float d = __fsub_rn(coord[((size_t)b * NN + nj) * 3 + j],
                                anchor_coord[((size_t)b * MM + mi) * 3 + j]);
            vv = __fdiv_rn(d, mn);
        } else {
            vv = feat[((size_t)b * NN + nj) * CC + (j - 3)]
               - anchor_feat[((size_t)b * MM + mi) * CC + (j - 3)];
        }
        xst[t] = vv;
    }
    __syncthreads();

    const int w = tid >> 6, lane = tid & 63;
    const int k0 = w * 8;   // this wave owns rows k0..k0+7; channel = lane

    // ---- stage 1: h1 = relu(LN(x @ W1 + b1)) ----
    const float bias1 = b1[lane];
    float acc[8];
    #pragma unroll
    for (int kk = 0; kk < 8; kk++) acc[kk] = bias1;
    #pragma unroll 4
    for (int j = 0; j < CIN; j++) {
        float wv = W1[j * H1 + lane];
        const float4 xa = *(const float4*)&xst[j * KNB + k0];
        const float4 xb = *(const float4*)&xst[j * KNB + k0 + 4];
        acc[0] = fmaf(xa.x, wv, acc[0]);
        acc[1] = fmaf(xa.y, wv, acc[1]);
        acc[2] = fmaf(xa.z, wv, acc[2]);
        acc[3] = fmaf(xa.w, wv, acc[3]);
        acc[4] = fmaf(xb.x, wv, acc[4]);
        acc[5] = fmaf(xb.y, wv, acc[5]);
        acc[6] = fmaf(xb.z, wv, acc[6]);
        acc[7] = fmaf(xb.w, wv, acc[7]);
    }
    const float g1v = g1[lane], be1v = be1[lane];
    #pragma unroll
    for (int kk = 0; kk < 8; kk++) {
        float vv = acc[kk];
        float s = vv, s2 = vv * vv;
        #pragma unroll
        for (int off = 32; off; off >>= 1) { s += __shfl_xor(s, off); s2 += __shfl_xor(s2, off); }
        float mu  = s  * (1.0f / H1);
        float var = s2 * (1.0f / H1) - mu * mu;
        float r = rsqrtf(var + 1e-6f);
        float y = fmaf((vv - mu) * r, g1v, be1v);
        h1t[lane * 36 + k0 + kk] = fmaxf(y, 0.0f);
    }
    __syncthreads();

    // ---- stage 2: h2 = relu(LN(h1 @ W2 + b2)), maxpool over k ----
    const float bias2a = b2[lane], bias2b = b2[lane + 64];
    float a[16];
    #pragma unroll
    for (int kk = 0; kk < 8; kk++) { a[kk] = bias2a; a[8 + kk] = bias2b; }
    #pragma unroll 4
    for (int j = 0; j < H1; j++) {
        float w0 = W2[j * H2 + lane];
        float w1 = W2[j * H2 + lane + 64];
        const float4 ha = *(const float4*)&h1t[j * 36 + k0];
        const float4 hb = *(const float4*)&h1t[j * 36 + k0 + 4];
        a[0] = fmaf(ha.x, w0, a[0]);   a[8]  = fmaf(ha.x, w1, a[8]);
        a[1] = fmaf(ha.y, w0, a[1]);   a[9]  = fmaf(ha.y, w1, a[9]);
        a[2] = fmaf(ha.z, w0, a[2]);   a[10] = fmaf(ha.z, w1, a[10]);
        a[3] = fmaf(ha.w, w0, a[3]);   a[11] = fmaf(ha.w, w1, a[11]);
        a[4] = fmaf(hb.x, w0, a[4]);   a[12] = fmaf(hb.x, w1, a[12]);
        a[5] = fmaf(hb.y, w0, a[5]);   a[13] = fmaf(hb.y, w1, a[13]);
        a[6] = fmaf(hb.z, w0, a[6]);   a[14] = fmaf(hb.z, w1, a[14]);
        a[7] = fmaf(hb.w, w0, a[7]);   a[15] = fmaf(hb.w, w1, a[15]);
    }
    const float g2a = g2[lane], g2b = g2[lane + 64];
    const float be2a = be2[lane], be2b = be2[lane + 64];
    float mx0 = -INFINITY, mx1 = -INFINITY;
    #pragma unroll
    for (int kk = 0; kk < 8; kk++) {
        float a0 = a[kk], a1 = a[8 + kk];
        float s = a0 + a1, s2 = a0 * a0 + a1 * a1;
        #pragma unroll
        for (int off = 32; off; off >>= 1) { s += __shfl_xor(s, off); s2 += __shfl_xor(s2, off); }
        float mu  = s  * (1.0f / H2);
        float var = s2 * (1.0f / H2) - mu * mu;
        float r = rsqrtf(var + 1e-6f);
        float y0 = fmaxf(fmaf((a0 - mu) * r, g2a, be2a), 0.0f);
        float y1 = fmaxf(fmaf((a1 - mu) * r, g2b, be2b), 0.0f);
        mx0 = fmaxf(mx0, y0);
        mx1 = fmaxf(mx1, y1);
    }
    pmax[w * H2 + lane]      = mx0;
    pmax[w * H2 + lane + 64] = mx1;
    __syncthreads();
    if (tid < H2) {
        float vv = pmax[tid];
        #pragma unroll
        for (int ww = 1; ww < 4; ww++) vv = fmaxf(vv, pmax[ww * H2 + tid]);
        out[(size_t)anchor * H2 + tid] = vv;
    }
}

extern "C" void kernel_launch(void* const* d_in, const int* in_sizes, int n_in,
                              void* d_out, int out_size, void* d_ws, size_t ws_size,
                              hipStream_t stream) {
    const float* feat         = (const float*)d_in[0];
    const float* coord        = (const float*)d_in[1];
    const float* anchor_feat  = (const float*)d_in[2];
    const float* anchor_coord = (const float*)d_in[3];
    const float* W1  = (const float*)d_in[4];
    const float* b1  = (const float*)d_in[5];
    const float* g1  = (const float*)d_in[6];
    const float* be1 = (const float*)d_in[7];
    const float* W2  = (const float*)d_in[8];
    const float* b2  = (const float*)d_in[9];
    const float* g2  = (const float*)d_in[10];
    const float* be2 = (const float*)d_in[11];
    float* out = (float*)d_out;

    int*   maxn   = (int*)d_ws;                       // 16 ints reserved
    int*   idxbuf = (int*)d_ws + 16;                  // BB*MM*KNB ints
    float* c2buf  = (float*)((int*)d_ws + 16 + BB * MM * KNB);  // BB*NN floats

    init_kernel<<<1, 64, 0, stream>>>(maxn);
    c2_kernel<<<(BB * NN + 255) / 256, 256, 0, stream>>>(coord, c2buf);
    knn_kernel<<<BB * MM, 256, 0, stream>>>(coord, anchor_coord, c2buf, idxbuf, maxn);
    mlp_kernel<<<BB * MM, 256, 0, stream>>>(feat, coord, anchor_feat, anchor_coord,
                                            W1, b1, g1, be1, W2, b2, g2, be2,
                                            maxn, idxbuf, out);
}

// Round 10
// 263.497 us; speedup vs baseline: 2.2192x; 1.0443x over previous
//
#include <hip/hip_runtime.h>
#include <math.h>

#define BB 4
#define NN 8192
#define MM 2048
#define CC 64
#define KNB 32
#define CIN 67   // 3 + CC
#define H1 64
#define H2 128
#define XP 36    // padded row stride for x^T / h1^T tiles (float4-aligned, breaks bank conflicts)

// ---------------- init: zero per-batch maxnorm cells ----------------
__global__ void init_kernel(int* maxnorm) {
    if (threadIdx.x < BB) maxnorm[threadIdx.x] = 0;
}

// ---------------- c2 precompute: sum of squares per point (validated round 6) ----------------
__global__ __launch_bounds__(256) void c2_kernel(const float* __restrict__ coord,
                                                 float* __restrict__ c2buf) {
    const int t = blockIdx.x * 256 + threadIdx.x;   // t in [0, BB*NN)
    if (t < BB * NN) {
        float cx = coord[t * 3 + 0], cy = coord[t * 3 + 1], cz = coord[t * 3 + 2];
        c2buf[t] = __fadd_rn(__fadd_rn(__fmul_rn(cx, cx), __fmul_rn(cy, cy)), __fmul_rn(cz, cz));
    }
}

// ---------------- kNN: one block per anchor; register radix select + U-prefilter ----------------
// Validated round 9. Selection math identical to round 7/8 (monotone u32 keys,
// 4x8-bit radix rank, <T emission + lowest-index ties).
__global__ __launch_bounds__(256, 4) void knn_kernel(
    const float* __restrict__ coord, const float* __restrict__ anchor_coord,
    const float* __restrict__ c2buf,
    int* __restrict__ idxbuf, int* __restrict__ maxnorm)
{
    __shared__ unsigned hist[4][256];     // per-wave histogram copies
    __shared__ unsigned wmax[4];
    __shared__ unsigned wtot[4];
    __shared__ unsigned bc[2];            // [0]=chosen bin, [1]=rank within bin
    __shared__ unsigned nsel;
    __shared__ int      selcell;
    __shared__ int      sel_s[KNB];

    const int anchor = blockIdx.x;
    const int b  = anchor >> 11;          // / MM
    const int mi = anchor & (MM - 1);
    const int tid = threadIdx.x;
    const int w = tid >> 6, lane = tid & 63;

    const float ax = anchor_coord[(b * MM + mi) * 3 + 0];
    const float ay = anchor_coord[(b * MM + mi) * 3 + 1];
    const float az = anchor_coord[(b * MM + mi) * 3 + 2];
    const float a2 = __fadd_rn(__fadd_rn(__fmul_rn(ax, ax), __fmul_rn(ay, ay)), __fmul_rn(az, az));

    const float* cb  = coord + (size_t)b * NN * 3;
    const float* c2b = c2buf + (size_t)b * NN;

    // distances (reference formula, bit-identical) -> monotone keys in REGISTERS
    unsigned kreg[32];
    unsigned tmin = 0xFFFFFFFFu;
    #pragma unroll
    for (int j = 0; j < 32; j++) {
        const int i = tid + 256 * j;      // thread's points: idx = tid + 256*j
        float cx = cb[i * 3 + 0], cy = cb[i * 3 + 1], cz = cb[i * 3 + 2];
        float c2 = c2b[i];
        float dt = __fadd_rn(__fadd_rn(__fmul_rn(ax, cx), __fmul_rn(ay, cy)), __fmul_rn(az, cz));
        float d2 = __fadd_rn(__fsub_rn(a2, __fmul_rn(2.0f, dt)), c2);
        unsigned ub = __float_as_uint(d2);
        ub ^= (unsigned)((int)ub >> 31) | 0x80000000u;   // monotone: u32 order == float order
        kreg[j] = ub;
        tmin = tmin < ub ? tmin : ub;
    }

    // U = max over 32 designated per-thread minima => T <= U (>=32 keys <= U)
    unsigned um = tmin;
    um = max(um, (unsigned)__shfl_xor((int)um, 1));
    um = max(um, (unsigned)__shfl_xor((int)um, 2));
    um = max(um, (unsigned)__shfl_xor((int)um, 4));
    if (lane == 0) wmax[w] = um;
    if (tid == 0) nsel = 0;
    __syncthreads();
    const unsigned U = max(max(wmax[0], wmax[1]), max(wmax[2], wmax[3]));

    unsigned prefix = 0, pmask = 0;
    unsigned k = KNB;                     // rank sought (1-indexed) among prefix-matching keys

    #pragma unroll
    for (int pass = 0; pass < 4; pass++) {
        const int sh = 24 - 8 * pass;
        unsigned* hf = &hist[0][0];
        hf[tid] = 0; hf[tid + 256] = 0; hf[tid + 512] = 0; hf[tid + 768] = 0;
        __syncthreads();
        #pragma unroll
        for (int j = 0; j < 32; j++) {
            unsigned kk = kreg[j];
            if (kk <= U && (kk & pmask) == prefix) atomicAdd(&hist[w][(kk >> sh) & 0xFFu], 1u);
        }
        __syncthreads();
        const unsigned h = hist[0][tid] + hist[1][tid] + hist[2][tid] + hist[3][tid];
        unsigned v = h;
        #pragma unroll
        for (int d = 1; d < 64; d <<= 1) {
            unsigned t = __shfl_up(v, d);
            if (lane >= d) v += t;
        }
        if (lane == 63) wtot[w] = v;
        __syncthreads();
        unsigned off = 0;
        #pragma unroll
        for (int ww = 0; ww < 3; ww++) if (ww < w) off += wtot[ww];
        v += off;
        const unsigned excl = v - h;
        if (excl < k && k <= v) { bc[0] = (unsigned)tid; bc[1] = k - excl; }
        __syncthreads();
        prefix |= bc[0] << sh;
        pmask  |= 0xFFu << sh;
        k = bc[1];
    }
    const unsigned T = prefix;            // exact key of the 32nd-smallest element

    // emission: all keys < T (set order irrelevant downstream)
    unsigned tiemask = 0;
    #pragma unroll
    for (int j = 0; j < 32; j++) {
        unsigned kk = kreg[j];
        if (kk < T) { unsigned pos = atomicAdd(&nsel, 1u); sel_s[pos] = tid + 256 * j; }
        else if (kk == T) tiemask |= 1u << j;
    }
    __syncthreads();
    const unsigned n_lt = nsel;
    const unsigned needed = KNB - n_lt;   // >= 1; ties taken in increasing index order
    int last = -1;
    for (unsigned r = 0; r < needed; r++) {
        if (tid == 0) selcell = 0x7fffffff;
        __syncthreads();
        unsigned m = tiemask;
        while (m) {
            int j = __ffs(m) - 1; m &= m - 1;
            int idx = tid + 256 * j;
            if (idx > last) atomicMin(&selcell, idx);
        }
        __syncthreads();
        last = selcell;
        if (tid == 0) sel_s[n_lt + r] = last;
        __syncthreads();
    }

    // write indices; per-batch max ||delta||
    float nrm = 0.0f;
    if (tid < KNB) {
        int j = sel_s[tid];
        idxbuf[anchor * KNB + tid] = j;
        float dx = __fsub_rn(cb[j * 3 + 0], ax);
        float dy = __fsub_rn(cb[j * 3 + 1], ay);
        float dz = __fsub_rn(cb[j * 3 + 2], az);
        nrm = sqrtf(dx * dx + dy * dy + dz * dz);
    }
    if (tid < 64) {
        #pragma unroll
        for (int off = 32; off; off >>= 1) nrm = fmaxf(nrm, __shfl_xor(nrm, off));
        if (tid == 0) atomicMax(&maxnorm[b], __float_as_int(nrm));
    }
}

// ---------------- fused gather + MLP + maxpool: one block per anchor ----------------
// Weights from global/L2 (validated round 5). NEW: coalesced gather — wave w loads
// neighbor k=8w+kk's 64 channels with lane=channel (one 256B coalesced load per
// (wave,k)), scalar-writes into x^T[j][k] with row stride 36. Values and compute
// order byte-identical to the validated kernel; only the load/store mapping changed.
__global__ __launch_bounds__(256, 6) void mlp_kernel(
    const float* __restrict__ feat, const float* __restrict__ coord,
    const float* __restrict__ anchor_feat, const float* __restrict__ anchor_coord,
    const float* __restrict__ W1, const float* __restrict__ b1,
    const float* __restrict__ g1, const float* __restrict__ be1,
    const float* __restrict__ W2, const float* __restrict__ b2,
    const float* __restrict__ g2, const float* __restrict__ be2,
    const int* __restrict__ maxnorm, const int* __restrict__ idxbuf,
    float* __restrict__ out)
{
    __shared__ __align__(16) float xst[CIN * XP];    // x transposed: [j][k], row stride 36
    __shared__ __align__(16) float h1t[H1 * XP];     // h1 transposed: [ch][k], row stride 36
    __shared__ int   sel[KNB];
    __shared__ float pmax[4 * H2];

    const int anchor = blockIdx.x;
    const int b  = anchor >> 11;
    const int mi = anchor & (MM - 1);
    const int tid = threadIdx.x;
    const int w = tid >> 6, lane = tid & 63;

    if (tid < KNB) sel[tid] = idxbuf[anchor * KNB + tid];
    __syncthreads();

    const float mn = __int_as_float(maxnorm[b]);

    // ---- coalesced gather: wave w owns neighbors k = 8w..8w+7; lane = feature channel ----
    {
        const float af = anchor_feat[((size_t)b * MM + mi) * CC + lane];
        #pragma unroll
        for (int kk = 0; kk < 8; kk++) {
            const int k = w * 8 + kk;
            const int nj = sel[k];
            float fv = feat[((size_t)b * NN + nj) * CC + lane] - af;
            xst[(3 + lane) * XP + k] = fv;
        }
    }
    if (tid < 128) {
        const int k = tid >> 2, j = tid & 3;
        if (j < 3) {
            const int nj = sel[k];
            float d = __fsub_rn(coord[((size_t)b * NN + nj) * 3 + j],
                                anchor_coord[((size_t)b * MM + mi) * 3 + j]);
            xst[j * XP + k] = __fdiv_rn(d, mn);
        }
    }
    __syncthreads();

    const int k0 = w * 8;   // this wave owns rows k0..k0+7; channel = lane

    // ---- stage 1: h1 = relu(LN(x @ W1 + b1)) ----
    const float bias1 = b1[lane];
    float acc[8];
    #pragma unroll
    for (int kk = 0; kk < 8; kk++) acc[kk] = bias1;
    #pragma unroll 4
    for (int j = 0; j < CIN; j++) {
        float wv = W1[j * H1 + lane];
        const float4 xa = *(const float4*)&xst[j * XP + k0];
        const float4 xb = *(const float4*)&xst[j * XP + k0 + 4];
        acc[0] = fmaf(xa.x, wv, acc[0]);
        acc[1] = fmaf(xa.y, wv, acc[1]);
        acc[2] = fmaf(xa.z, wv, acc[2]);
        acc[3] = fmaf(xa.w, wv, acc[3]);
        acc[4] = fmaf(xb.x, wv, acc[4]);
        acc[5] = fmaf(xb.y, wv, acc[5]);
        acc[6] = fmaf(xb.z, wv, acc[6]);
        acc[7] = fmaf(xb.w, wv, acc[7]);
    }
    const float g1v = g1[lane], be1v = be1[lane];
    #pragma unroll
    for (int kk = 0; kk < 8; kk++) {
        float vv = acc[kk];
        float s = vv, s2 = vv * vv;
        #pragma unroll
        for (int off = 32; off; off >>= 1) { s += __shfl_xor(s, off); s2 += __shfl_xor(s2, off); }
        float mu  = s  * (1.0f / H1);
        float var = s2 * (1.0f / H1) - mu * mu;
        float r = rsqrtf(var + 1e-6f);
        float y = fmaf((vv - mu) * r, g1v, be1v);
        h1t[lane * XP + k0 + kk] = fmaxf(y, 0.0f);
    }
    __syncthreads();

    // ---- stage 2: h2 = relu(LN(h1 @ W2 + b2)), maxpool over k ----
    const float bias2a = b2[lane], bias2b = b2[lane + 64];
    float a[16];
    #pragma unroll
    for (int kk = 0; kk < 8; kk++) { a[kk] = bias2a; a[8 + kk] = bias2b; }
    #pragma unroll 4
    for (int j = 0; j < H1; j++) {
        float w0 = W2[j * H2 + lane];
        float w1 = W2[j * H2 + lane + 64];
        const float4 ha = *(const float4*)&h1t[j * XP + k0];
        const float4 hb = *(const float4*)&h1t[j * XP + k0 + 4];
        a[0] = fmaf(ha.x, w0, a[0]);   a[8]  = fmaf(ha.x, w1, a[8]);
        a[1] = fmaf(ha.y, w0, a[1]);   a[9]  = fmaf(ha.y, w1, a[9]);
        a[2] = fmaf(ha.z, w0, a[2]);   a[10] = fmaf(ha.z, w1, a[10]);
        a[3] = fmaf(ha.w, w0, a[3]);   a[11] = fmaf(ha.w, w1, a[11]);
        a[4] = fmaf(hb.x, w0, a[4]);   a[12] = fmaf(hb.x, w1, a[12]);
        a[5] = fmaf(hb.y, w0, a[5]);   a[13] = fmaf(hb.y, w1, a[13]);
        a[6] = fmaf(hb.z, w0, a[6]);   a[14] = fmaf(hb.z, w1, a[14]);
        a[7] = fmaf(hb.w, w0, a[7]);   a[15] = fmaf(hb.w, w1, a[15]);
    }
    const float g2a = g2[lane], g2b = g2[lane + 64];
    const float be2a = be2[lane], be2b = be2[lane + 64];
    float mx0 = -INFINITY, mx1 = -INFINITY;
    #pragma unroll
    for (int kk = 0; kk < 8; kk++) {
        float a0 = a[kk], a1 = a[8 + kk];
        float s = a0 + a1, s2 = a0 * a0 + a1 * a1;
        #pragma unroll
        for (int off = 32; off; off >>= 1) { s += __shfl_xor(s, off); s2 += __shfl_xor(s2, off); }
        float mu  = s  * (1.0f / H2);
        float var = s2 * (1.0f / H2) - mu * mu;
        float r = rsqrtf(var + 1e-6f);
        float y0 = fmaxf(fmaf((a0 - mu) * r, g2a, be2a), 0.0f);
        float y1 = fmaxf(fmaf((a1 - mu) * r, g2b, be2b), 0.0f);
        mx0 = fmaxf(mx0, y0);
        mx1 = fmaxf(mx1, y1);
    }
    pmax[w * H2 + lane]      = mx0;
    pmax[w * H2 + lane + 64] = mx1;
    __syncthreads();
    if (tid < H2) {
        float vv = pmax[tid];
        #pragma unroll
        for (int ww = 1; ww < 4; ww++) vv = fmaxf(vv, pmax[ww * H2 + tid]);
        out[(size_t)anchor * H2 + tid] = vv;
    }
}

extern "C" void kernel_launch(void* const* d_in, const int* in_sizes, int n_in,
                              void* d_out, int out_size, void* d_ws, size_t ws_size,
                              hipStream_t stream) {
    const float* feat         = (const float*)d_in[0];
    const float* coord        = (const float*)d_in[1];
    const float* anchor_feat  = (const float*)d_in[2];
    const float* anchor_coord = (const float*)d_in[3];
    const float* W1  = (const float*)d_in[4];
    const float* b1  = (const float*)d_in[5];
    const float* g1  = (const float*)d_in[6];
    const float* be1 = (const float*)d_in[7];
    const float* W2  = (const float*)d_in[8];
    const float* b2  = (const float*)d_in[9];
    const float* g2  = (const float*)d_in[10];
    const float* be2 = (const float*)d_in[11];
    float* out = (float*)d_out;

    int*   maxn   = (int*)d_ws;                       // 16 ints reserved
    int*   idxbuf = (int*)d_ws + 16;                  // BB*MM*KNB ints
    float* c2buf  = (float*)((int*)d_ws + 16 + BB * MM * KNB);  // BB*NN floats

    init_kernel<<<1, 64, 0, stream>>>(maxn);
    c2_kernel<<<(BB * NN + 255) / 256, 256, 0, stream>>>(coord, c2buf);
    knn_kernel<<<BB * MM, 256, 0, stream>>>(coord, anchor_coord, c2buf, idxbuf, maxn);
    mlp_kernel<<<BB * MM, 256, 0, stream>>>(feat, coord, anchor_feat, anchor_coord,
                                            W1, b1, g1, be1, W2, b2, g2, be2,
                                            maxn, idxbuf, out);
}